// Round 4
// baseline (47.621 us; speedup 1.0000x reference)
//
#include <hip/hip_runtime.h>
#include <stdint.h>

// Soft decision-tree ensemble, collapsed to:
//   out[b,c] = sum_t ( A'[t,c] + sum_{k<4} d[b,t,k]*B'[t,k,c] ) / (4 + d[b,t,3] + 1e-8)
//   d[b,t,k] = sigmoid( X[b,:] . W[t,k,:] + bias[t,k] ),  nodes 0..3 only.
// GEMM 65536x512 @ 512x256, fp16 MFMA, memory-bound on X (134 MB fp32 read once).
// R4: DRAM-locality fix. Block = 256 rows as 8 panels x 32 rows x full K.
//     Per panel: one CONTIGUOUS 64KB X read -> LDS f16 (dbuf). W entirely in
//     VGPRs (f16x8 Wf[16][2] per wave, 32 cols/wave). Raw barriers only;
//     panel p+1 loads in flight across compute+epilogue.

#define KDIM 512
#define PPT 3607
#define NP 8            // panels per block
#define EPI_S 260       // E row stride (f32): 1040B, 16B-aligned, conflict-free float4 reads
#define E_OFF 65536
#define P_OFF 98816     // E: 32*260*4 = 33280
#define P_S 34
#define AB_OFF 103168   // P: 32*34*4 = 4352
#define LDS_BYTES 105728

typedef _Float16 f16x8 __attribute__((ext_vector_type(8)));
typedef float f32x4 __attribute__((ext_vector_type(4)));

__global__ __launch_bounds__(128) void prep_kernel(const float* __restrict__ p,
                                                   const float* __restrict__ tw,
                                                   _Float16* __restrict__ Wh,
                                                   float* __restrict__ biasN,
                                                   float* __restrict__ AB) {
    const int c = blockIdx.x;          // 0..255
    const int t = c >> 2, i = c & 3;
    const float* wsrc = p + t * PPT + i * KDIM;
    for (int k = threadIdx.x; k < KDIM; k += 128)
        Wh[c * KDIM + k] = (_Float16)wsrc[k];
    if (threadIdx.x == 0)
        biasN[c] = p[t * PPT + 7 * KDIM + i];
    if (threadIdx.x == 64 && c < 64) {
        const int tt = c;
        const float* lg = p + tt * PPT + 7 * 513;   // leaf logits, 8 x 2
        const float w = tw[tt];
        float ld[8][2];
#pragma unroll
        for (int j = 0; j < 8; ++j) {
            float a = lg[2 * j], b = lg[2 * j + 1];
            float m = fmaxf(a, b);
            float e0 = expf(a - m), e1 = expf(b - m);
            float s = e0 + e1;
            ld[j][0] = e0 / s; ld[j][1] = e1 / s;
        }
        float* o = AB + tt * 10;
#pragma unroll
        for (int cc = 0; cc < 2; ++cc) {
            o[0 + cc] = w * (ld[0][cc] + ld[2][cc] + ld[4][cc] + ld[6][cc]);
            o[2 + cc] = w * (ld[1][cc] - ld[2][cc]);
            o[4 + cc] = w * (ld[3][cc] - ld[4][cc]);
            o[6 + cc] = w * (ld[5][cc] - ld[6][cc]);
            o[8 + cc] = w * (ld[7][cc]);
        }
    }
}

__device__ __forceinline__ f16x8 cvt8(float4 a, float4 b) {
    f16x8 h;
    h[0] = (_Float16)a.x; h[1] = (_Float16)a.y; h[2] = (_Float16)a.z; h[3] = (_Float16)a.w;
    h[4] = (_Float16)b.x; h[5] = (_Float16)b.y; h[6] = (_Float16)b.z; h[7] = (_Float16)b.w;
    return h;
}

// LDS: xbuf[2] f16 [32 rows][512 k] at b*32768; 16B-granule swizzle g' = g ^ (row&15)
//      E f32 [32][260] at E_OFF; P f32 [32][34] at P_OFF; AB f32[640] at AB_OFF
__global__ __launch_bounds__(512, 2) void main_kernel(const float* __restrict__ X,
                                                      const _Float16* __restrict__ Wh,
                                                      const float* __restrict__ biasN,
                                                      const float* __restrict__ ABg,
                                                      float* __restrict__ out) {
    extern __shared__ char smem[];
    const int tid = threadIdx.x;
    const int lane = tid & 63;
    const int wn = tid >> 6;          // wave 0..7 : owns cols wn*32 .. +31
    const int r15 = lane & 15;
    const int hi = lane >> 4;         // 0..3
    const int gr0 = blockIdx.x * 256; // 256 rows per block

    // AB coeffs -> LDS (read only in epilogues, after barriers)
    {
        float* abl = (float*)(smem + AB_OFF);
        for (int i = tid; i < 640; i += 512) abl[i] = ABg[i];
    }

    // ---- W into registers: wave wn holds cols wn*32..+31, all K ----
    f16x8 Wf[16][2];
#pragma unroll
    for (int s = 0; s < 16; ++s)
#pragma unroll
        for (int ct = 0; ct < 2; ++ct)
            Wf[s][ct] = *(const f16x8*)&Wh[(size_t)(wn * 32 + ct * 16 + r15) * KDIM + s * 32 + hi * 8];

    float bl[2];
#pragma unroll
    for (int ct = 0; ct < 2; ++ct) bl[ct] = biasN[wn * 32 + ct * 16 + r15];

    // ---- X staging map: chunk = i*512 + tid covers bytes [chunk*32, +32) of the panel ----
    // row = chunk>>6 (0..31), g = chunk&63 (16B granule), swizzled g' = g ^ (row&15)
    int srow[4], ldw[4];
#pragma unroll
    for (int i = 0; i < 4; ++i) {
        int chunk = i * 512 + tid;
        int row = chunk >> 6, g = chunk & 63;
        srow[i] = chunk * 8;                                   // f32 offset in panel
        ldw[i] = row * 1024 + ((g ^ (row & 15)) << 4);         // byte offset in xbuf
    }

    // A-frag read constants: row = rt*16 + r15, g = s*4 + hi, g' = g ^ r15
    const int aoff0 = r15 * 1024;             // rt=0 (rows 0..15)
    const int aoff1 = (16 + r15) * 1024;      // rt=1 (rows 16..31)

    const float* Xblk = X + (size_t)gr0 * KDIM;
    float4 xr[8];

    // prologue: issue panel-0 loads
#pragma unroll
    for (int i = 0; i < 4; ++i) {
        xr[2 * i]     = *(const float4*)(Xblk + srow[i]);
        xr[2 * i + 1] = *(const float4*)(Xblk + srow[i] + 4);
    }

    for (int p = 0; p < NP; ++p) {
        char* xb = smem + (p & 1) * 32768;
        // stage panel p (compiler inserts precise vmcnt for xr deps)
#pragma unroll
        for (int i = 0; i < 4; ++i)
            *(f16x8*)(xb + ldw[i]) = cvt8(xr[2 * i], xr[2 * i + 1]);
        // issue panel p+1 loads (stay in flight across barrier/compute/epilogue)
        if (p + 1 < NP) {
            const float* Xp = Xblk + (size_t)(p + 1) * 32 * KDIM;
#pragma unroll
            for (int i = 0; i < 4; ++i) {
                xr[2 * i]     = *(const float4*)(Xp + srow[i]);
                xr[2 * i + 1] = *(const float4*)(Xp + srow[i] + 4);
            }
        }
        asm volatile("s_waitcnt lgkmcnt(0)" ::: "memory");   // ds_writes visible; loads NOT drained
        __builtin_amdgcn_s_barrier();

        // ---- compute panel p: 16 k-steps, 2 row-tiles x 2 col-tiles ----
        f32x4 acc[2][2];
#pragma unroll
        for (int rt = 0; rt < 2; ++rt)
#pragma unroll
            for (int ct = 0; ct < 2; ++ct)
                acc[rt][ct] = (f32x4){0.f, 0.f, 0.f, 0.f};
#pragma unroll
        for (int s = 0; s < 16; ++s) {
            const int go = ((s * 4 + hi) ^ r15) << 4;
            f16x8 a0 = *(const f16x8*)(xb + aoff0 + go);
            f16x8 a1 = *(const f16x8*)(xb + aoff1 + go);
            acc[0][0] = __builtin_amdgcn_mfma_f32_16x16x32_f16(a0, Wf[s][0], acc[0][0], 0, 0, 0);
            acc[0][1] = __builtin_amdgcn_mfma_f32_16x16x32_f16(a0, Wf[s][1], acc[0][1], 0, 0, 0);
            acc[1][0] = __builtin_amdgcn_mfma_f32_16x16x32_f16(a1, Wf[s][0], acc[1][0], 0, 0, 0);
            acc[1][1] = __builtin_amdgcn_mfma_f32_16x16x32_f16(a1, Wf[s][1], acc[1][1], 0, 0, 0);
        }

        // ---- epilogue: sigmoid -> E (transpose via LDS) -> tree-reduce -> out ----
        float* Ef = (float*)(smem + E_OFF);
#pragma unroll
        for (int rt = 0; rt < 2; ++rt)
#pragma unroll
            for (int ct = 0; ct < 2; ++ct) {
                const int col = wn * 32 + ct * 16 + r15;
#pragma unroll
                for (int reg = 0; reg < 4; ++reg) {
                    const int row = rt * 16 + hi * 4 + reg;
                    float z = acc[rt][ct][reg] + bl[ct];
                    Ef[row * EPI_S + col] = __builtin_amdgcn_rcpf(1.f + __expf(-z));
                }
            }
        asm volatile("s_waitcnt lgkmcnt(0)" ::: "memory");
        __builtin_amdgcn_s_barrier();
        {   // thread t: row t>>4, tree-group t&15 (4 trees each)
            const float* abl = (const float*)(smem + AB_OFF);
            float* Pf = (float*)(smem + P_OFF);
            const int row = tid >> 4, tg = tid & 15;
            float s0 = 0.f, s1 = 0.f;
#pragma unroll
            for (int j = 0; j < 4; ++j) {
                const int t = tg * 4 + j;
                float4 dv = *(const float4*)&Ef[row * EPI_S + t * 4];
                const float* abt = &abl[t * 10];
                float inv = __builtin_amdgcn_rcpf(4.f + dv.w + 1e-8f);
                s0 += (abt[0] + dv.x * abt[2] + dv.y * abt[4] + dv.z * abt[6] + dv.w * abt[8]) * inv;
                s1 += (abt[1] + dv.x * abt[3] + dv.y * abt[5] + dv.z * abt[7] + dv.w * abt[9]) * inv;
            }
            Pf[row * P_S + tg * 2 + 0] = s0;
            Pf[row * P_S + tg * 2 + 1] = s1;
        }
        asm volatile("s_waitcnt lgkmcnt(0)" ::: "memory");
        __builtin_amdgcn_s_barrier();
        if (tid < 64) {
            const float* Pf = (const float*)(smem + P_OFF);
            const int row = tid >> 1, c = tid & 1;
            float s = 0.f;
#pragma unroll
            for (int tg = 0; tg < 16; ++tg) s += Pf[row * P_S + tg * 2 + c];
            out[(size_t)(gr0 + p * 32 + row) * 2 + c] = s;
        }
        // no barrier needed: next panel writes xbuf[(p+1)&1] (dead) and
        // E/P writes of p+1 are ordered behind p+1's own barriers.
    }
}

extern "C" void kernel_launch(void* const* d_in, const int* in_sizes, int n_in,
                              void* d_out, int out_size, void* d_ws, size_t ws_size,
                              hipStream_t stream) {
    const float* x  = (const float*)d_in[0];
    const float* tp = (const float*)d_in[1];
    const float* tw = (const float*)d_in[2];
    float* out = (float*)d_out;

    _Float16* Wh = (_Float16*)d_ws;
    float* biasN = (float*)((char*)d_ws + 262144);
    float* AB    = (float*)((char*)d_ws + 263168);

    (void)hipFuncSetAttribute((const void*)reinterpret_cast<const void*>(&main_kernel),
                              hipFuncAttributeMaxDynamicSharedMemorySize, LDS_BYTES);

    prep_kernel<<<256, 128, 0, stream>>>(tp, tw, Wh, biasN, AB);
    main_kernel<<<256, 512, LDS_BYTES, stream>>>(x, Wh, biasN, AB, out);
}